// Round 1
// baseline (12586.433 us; speedup 1.0000x reference)
//
#include <hip/hip_runtime.h>

#define CI_STRIDE 262144   // 64^3 floats between channels
#define NELEM     16777216 // 64^4
#define NWP       12288    // float4 entries per pass weight: 64ci*3dy*64co

// 64 MB scratch buffer (layout-swapped tensor) + prepared weights
__device__ float  g_buf[NELEM];
__device__ float4 g_wt[6 * NWP];

// Prepare weights: g_wt[p][(ci*3+dy)*64+co] = {W[dy][0],W[dy][1],W[dy][2],0}
// For passes 4,5 (FB/BF run in swapped layout) the kernel spatial dims are
// transposed: {w[co][ci][0][dy], w[co][ci][1][dy], w[co][ci][2][dy], 0}
__global__ __launch_bounds__(256) void prep_weights(
    const float* __restrict__ w0, const float* __restrict__ w1,
    const float* __restrict__ w2, const float* __restrict__ w3,
    const float* __restrict__ w4, const float* __restrict__ w5)
{
    int tid = blockIdx.x * 256 + threadIdx.x;
    if (tid >= 6 * NWP) return;
    int p  = tid / NWP;
    int r  = tid % NWP;
    int co = r & 63;
    int q  = r >> 6;
    int dy = q % 3;
    int ci = q / 3;
    const float* src = (p == 0) ? w0 : (p == 1) ? w1 : (p == 2) ? w2
                      : (p == 3) ? w3 : (p == 4) ? w4 : w5;
    int base = co * 576 + ci * 9;
    float a, b, c;
    if (p < 4) {
        a = src[base + dy * 3 + 0];
        b = src[base + dy * 3 + 1];
        c = src[base + dy * 3 + 2];
    } else {
        a = src[base + 0 + dy];
        b = src[base + 3 + dy];
        c = src[base + 6 + dy];
    }
    g_wt[tid] = make_float4(a, b, c, 0.f);
}

// Swap last two dims: in[o][a][b] -> out[o][b][a], o in [0,4096), a,b = 64
__global__ __launch_bounds__(256) void transpose_hw(
    const float* __restrict__ in, float* __restrict__ out)
{
    __shared__ float t[64][65];
    const size_t base = (size_t)blockIdx.x * 4096;
    const int c  = threadIdx.x & 63;
    const int r4 = threadIdx.x >> 6; // 0..3
#pragma unroll
    for (int r = 0; r < 16; ++r) {
        int a = r4 * 16 + r;
        t[a][c] = in[base + a * 64 + c];
    }
    __syncthreads();
#pragma unroll
    for (int r = 0; r < 16; ++r) {
        int b = r4 * 16 + r;
        out[base + (size_t)b * 64 + c] = t[c][b];
    }
}

// One scan step: buf[t_cur] += relu(conv3x3(buf[t_prev]))
// Geometry: slice stride st, conv-row stride su, conv-col stride 1.
// Block: 4 waves; wave = one conv-row u, 4 output columns v0..v0+3, all 64 co
// (lane = co). Grid: 256 blocks (16 u-tiles x 16 v-tiles).
__global__ __launch_bounds__(256) void step_kernel(
    float* __restrict__ buf, const float4* __restrict__ wt,
    int t_cur, int t_prev, int st, int su)
{
    const int lane = threadIdx.x & 63;
    const int wid  = threadIdx.x >> 6;
    const int b    = blockIdx.x;
    const int u    = __builtin_amdgcn_readfirstlane(((b & 15) << 2) + wid);
    const int v0   = __builtin_amdgcn_readfirstlane((b >> 4) << 2);

    const float* prev = buf + (size_t)t_prev * st;
    float acc0 = 0.f, acc1 = 0.f, acc2 = 0.f, acc3 = 0.f;

    for (int cc = 0; cc < 8; ++cc) {
        float4 W[8][3];
#pragma unroll
        for (int i = 0; i < 8; ++i)
#pragma unroll
            for (int dy = 0; dy < 3; ++dy)
                W[i][dy] = wt[((cc * 8 + i) * 3 + dy) * 64 + lane];

#pragma unroll
        for (int i = 0; i < 8; ++i) {
            const int ci = cc * 8 + i;
            const float* cbase = prev + (size_t)ci * CI_STRIDE;
#pragma unroll
            for (int dy = 0; dy < 3; ++dy) {
                const int uu = u + dy - 1;
                if (uu < 0 || uu > 63) continue; // zero padding (uniform branch)
                const float* rp = cbase + (size_t)uu * su + v0;
                // window win[m] = input at column v0 + m - 1
                float4 mid = *(const float4*)rp; // columns v0..v0+3 (16B aligned)
                float w0 = 0.f, w5 = 0.f;
                if (v0 != 0)  w0 = rp[-1];
                if (v0 != 60) w5 = rp[4];
                const float4 k = W[i][dy];
                acc0 = fmaf(w0,    k.x, fmaf(mid.x, k.y, fmaf(mid.y, k.z, acc0)));
                acc1 = fmaf(mid.x, k.x, fmaf(mid.y, k.y, fmaf(mid.z, k.z, acc1)));
                acc2 = fmaf(mid.y, k.x, fmaf(mid.z, k.y, fmaf(mid.w, k.z, acc2)));
                acc3 = fmaf(mid.z, k.x, fmaf(mid.w, k.y, fmaf(w5,    k.z, acc3)));
            }
        }
    }

    float* cur = buf + (size_t)t_cur * st + (size_t)lane * CI_STRIDE
               + (size_t)u * su + v0;
    cur[0] += fmaxf(acc0, 0.f);
    cur[1] += fmaxf(acc1, 0.f);
    cur[2] += fmaxf(acc2, 0.f);
    cur[3] += fmaxf(acc3, 0.f);
}

extern "C" void kernel_launch(void* const* d_in, const int* in_sizes, int n_in,
                              void* d_out, int out_size, void* d_ws, size_t ws_size,
                              hipStream_t stream)
{
    (void)in_sizes; (void)n_in; (void)out_size; (void)d_ws; (void)ws_size;
    const float* x = (const float*)d_in[0];
    float* out = (float*)d_out;

    void* pb = nullptr; void* pw = nullptr;
    hipGetSymbolAddress(&pb, HIP_SYMBOL(g_buf));
    hipGetSymbolAddress(&pw, HIP_SYMBOL(g_wt));
    float*  bufB = (float*)pb;
    float4* wt   = (float4*)pw;

    prep_weights<<<288, 256, 0, stream>>>(
        (const float*)d_in[1], (const float*)d_in[2], (const float*)d_in[3],
        (const float*)d_in[4], (const float*)d_in[5], (const float*)d_in[6]);

    hipMemcpyAsync(out, x, (size_t)NELEM * sizeof(float),
                   hipMemcpyDeviceToDevice, stream);

    // Pass 1: UD (tdim=3, forward). Layout0 [k][d][h][w]: t=h (64), u=d (4096), v=w (1)
    for (int t = 1; t < 64; ++t)
        step_kernel<<<256, 256, 0, stream>>>(out, wt + 0 * NWP, t, t - 1, 64, 4096);
    // Pass 2: DU (tdim=3, reverse)
    for (int t = 62; t >= 0; --t)
        step_kernel<<<256, 256, 0, stream>>>(out, wt + 1 * NWP, t, t + 1, 64, 4096);

    // Swap H<->W: layout1 [k][d][w][h]
    transpose_hw<<<4096, 256, 0, stream>>>(out, bufB);

    // Pass 3: LR (tdim=4, forward). Layout1: t=w (64), u=d (4096), v=h (1)
    for (int t = 1; t < 64; ++t)
        step_kernel<<<256, 256, 0, stream>>>(bufB, wt + 2 * NWP, t, t - 1, 64, 4096);
    // Pass 4: RL (tdim=4, reverse)
    for (int t = 62; t >= 0; --t)
        step_kernel<<<256, 256, 0, stream>>>(bufB, wt + 3 * NWP, t, t + 1, 64, 4096);

    // Pass 5: FB (tdim=2, forward). Layout1: t=d (4096), u=w (64), v=h (1),
    // weights spatially transposed (handled in prep_weights p>=4)
    for (int t = 1; t < 64; ++t)
        step_kernel<<<256, 256, 0, stream>>>(bufB, wt + 4 * NWP, t, t - 1, 4096, 64);
    // Pass 6: BF (tdim=2, reverse)
    for (int t = 62; t >= 0; --t)
        step_kernel<<<256, 256, 0, stream>>>(bufB, wt + 5 * NWP, t, t + 1, 4096, 64);

    // Swap back to layout0 into d_out
    transpose_hw<<<4096, 256, 0, stream>>>(bufB, out);
}